// Round 5
// baseline (107.607 us; speedup 1.0000x reference)
//
#include <hip/hip_runtime.h>

// DIAGNOSTIC ROUND: round-2 kernel with compute repeated PASSES times
// (idempotent stores, CSE broken by opaque v_mov). Purpose: (1) get the kernel
// into rocprof's top-5 dispatches (fills at ~40us were masking it), (2) the
// scaling slope dur = F + PASSES*C separates fixed overhead F from compute C.
//
// out[t][j] = b[j] + sum_d W[j][d] * sum_{h,c} A[d][h][c]*cos(w[d][h][c]*s_t + phi[d][h][c])

constexpr int S_PTS  = 32768;
constexpr int DIM    = 64;
constexpr int HC     = 32;   // H*2
constexpr int TPW    = 16;   // time points per wave
constexpr int PASSES = 8;    // diagnostic repeat factor
constexpr float INV_2PI = 0.15915494309189535f;

__global__ __launch_bounds__(256, 2)
void fourier_fused(const float* __restrict__ s,
                   const float* __restrict__ A,
                   const float* __restrict__ phi,
                   const float* __restrict__ w,
                   const float* __restrict__ Wm,
                   const float* __restrict__ b,
                   float* __restrict__ out)
{
    __shared__ float pres[4][TPW][DIM];   // 16 KiB, wave-private slabs

    const int lane = threadIdx.x & 63;
    const int wid  = threadIdx.x >> 6;
    const int gw   = blockIdx.x * 4 + wid;
    const int t0   = gw * TPW;

    // ---- per-lane Fourier params (lane = d), freqs/phases in revolutions ----
    float a_r[HC], w_r[HC], p_r[HC];
    {
        const float4* A4 = reinterpret_cast<const float4*>(A   + lane * HC);
        const float4* P4 = reinterpret_cast<const float4*>(phi + lane * HC);
        const float4* W4 = reinterpret_cast<const float4*>(w   + lane * HC);
        #pragma unroll
        for (int q = 0; q < HC / 4; ++q) {
            float4 av = A4[q], pv = P4[q], wv = W4[q];
            a_r[4*q+0] = av.x; a_r[4*q+1] = av.y; a_r[4*q+2] = av.z; a_r[4*q+3] = av.w;
            p_r[4*q+0] = pv.x * INV_2PI; p_r[4*q+1] = pv.y * INV_2PI;
            p_r[4*q+2] = pv.z * INV_2PI; p_r[4*q+3] = pv.w * INV_2PI;
            w_r[4*q+0] = wv.x * INV_2PI; w_r[4*q+1] = wv.y * INV_2PI;
            w_r[4*q+2] = wv.z * INV_2PI; w_r[4*q+3] = wv.w * INV_2PI;
        }
    }

    // ---- W row + bias (lane = j), loaded once ----
    float Wrow[DIM];
    {
        const float4* Wr4 = reinterpret_cast<const float4*>(Wm + lane * DIM);
        #pragma unroll
        for (int q = 0; q < DIM / 4; ++q) {
            float4 v = Wr4[q];
            Wrow[4*q+0] = v.x; Wrow[4*q+1] = v.y; Wrow[4*q+2] = v.z; Wrow[4*q+3] = v.w;
        }
    }
    const float bj = b[lane];

    // lanes 0..15 hold the wave's 16 time values
    const float sv = s[t0 + (lane & (TPW - 1))];
    float* slab = &pres[wid][0][0];

    #pragma unroll 1
    for (int pass = 0; pass < PASSES; ++pass) {
        float svp = sv;
        // opaque register copy: breaks CSE so each pass recomputes everything
        asm volatile("v_mov_b32 %0, %0" : "+v"(svp));

        // ---- phase A: 16 Fourier sums into registers ----
        float pr[TPW];
        #pragma unroll
        for (int k = 0; k < TPW; ++k) {
            const float st = __uint_as_float(__builtin_amdgcn_readlane(__float_as_uint(svp), k));
            float ac0 = 0.f, ac1 = 0.f, ac2 = 0.f, ac3 = 0.f;
            #pragma unroll
            for (int i = 0; i < HC; i += 4) {
                ac0 = fmaf(a_r[i+0], __builtin_amdgcn_cosf(fmaf(w_r[i+0], st, p_r[i+0])), ac0);
                ac1 = fmaf(a_r[i+1], __builtin_amdgcn_cosf(fmaf(w_r[i+1], st, p_r[i+1])), ac1);
                ac2 = fmaf(a_r[i+2], __builtin_amdgcn_cosf(fmaf(w_r[i+2], st, p_r[i+2])), ac2);
                ac3 = fmaf(a_r[i+3], __builtin_amdgcn_cosf(fmaf(w_r[i+3], st, p_r[i+3])), ac3);
            }
            pr[k] = (ac0 + ac1) + (ac2 + ac3);
        }

        // ---- phase B: stage slab (wave-synchronous; guard against prior pass reads) ----
        asm volatile("s_waitcnt lgkmcnt(0)" ::: "memory");
        #pragma unroll
        for (int k = 0; k < TPW; ++k) slab[k * DIM + lane] = pr[k];
        asm volatile("s_waitcnt lgkmcnt(0)" ::: "memory");

        // ---- phase C: 16 independent matvecs, 4 accumulators ----
        #pragma unroll
        for (int k = 0; k < TPW; ++k) {
            const float* row = slab + k * DIM;
            float o0 = bj, o1 = 0.f, o2 = 0.f, o3 = 0.f;
            #pragma unroll
            for (int d = 0; d < DIM; d += 16) {
                float4 p0 = *reinterpret_cast<const float4*>(row + d + 0);
                float4 p1 = *reinterpret_cast<const float4*>(row + d + 4);
                float4 p2 = *reinterpret_cast<const float4*>(row + d + 8);
                float4 p3 = *reinterpret_cast<const float4*>(row + d + 12);
                o0 = fmaf(p0.x, Wrow[d+ 0], o0); o0 = fmaf(p0.y, Wrow[d+ 1], o0);
                o0 = fmaf(p0.z, Wrow[d+ 2], o0); o0 = fmaf(p0.w, Wrow[d+ 3], o0);
                o1 = fmaf(p1.x, Wrow[d+ 4], o1); o1 = fmaf(p1.y, Wrow[d+ 5], o1);
                o1 = fmaf(p1.z, Wrow[d+ 6], o1); o1 = fmaf(p1.w, Wrow[d+ 7], o1);
                o2 = fmaf(p2.x, Wrow[d+ 8], o2); o2 = fmaf(p2.y, Wrow[d+ 9], o2);
                o2 = fmaf(p2.z, Wrow[d+10], o2); o2 = fmaf(p2.w, Wrow[d+11], o2);
                o3 = fmaf(p3.x, Wrow[d+12], o3); o3 = fmaf(p3.y, Wrow[d+13], o3);
                o3 = fmaf(p3.z, Wrow[d+14], o3); o3 = fmaf(p3.w, Wrow[d+15], o3);
            }
            out[(t0 + k) * DIM + lane] = (o0 + o1) + (o2 + o3);  // idempotent across passes
        }
    }
}

extern "C" void kernel_launch(void* const* d_in, const int* in_sizes, int n_in,
                              void* d_out, int out_size, void* d_ws, size_t ws_size,
                              hipStream_t stream) {
    const float* s   = (const float*)d_in[0];
    // d_in[1] is x — unused by the forward pass
    const float* A   = (const float*)d_in[2];
    const float* phi = (const float*)d_in[3];
    const float* w   = (const float*)d_in[4];
    const float* Wm  = (const float*)d_in[5];
    const float* b   = (const float*)d_in[6];
    float* out = (float*)d_out;

    dim3 grid(S_PTS / (4 * TPW));  // 512 blocks x 4 waves x 16 t = 32768
    dim3 block(256);
    hipLaunchKernelGGL(fourier_fused, grid, block, 0, stream,
                       s, A, phi, w, Wm, b, out);
}

// Round 6
// 17.483 us; speedup vs baseline: 6.1551x; 6.1551x over previous
//
#include <hip/hip_runtime.h>

// CoupledFourierSystem: out[t][j] = b[j] + sum_d W[j][d] * sum_{h,c} A[d][h][c]*cos(w[d][h][c]*s_t + phi[d][h][c])
// S=32768, DIM=64, H=16 (HC=32)
//
// Per wave (16 time points):
//   phase A: lane=d computes pre[t][d] = sum_hc a*cos(w'*s_t + p') with packed
//            v_pk_fma_f32; 16 swizzled ds_write_b32 into a wave-private slab.
//   phase C: P[16x64] @ W^T[64x64] as 8x v_mfma_f32_16x16x32_f16.
//            A-frags: 4 swizzled ds_read_b128 + cvt_pkrtz (vs 256 broadcast
//            reads before -- the diagnosed LDS-pipe saturation).
//            B-frags (W) + bias live in registers, loaded once.

typedef float    f32x2 __attribute__((ext_vector_type(2)));
typedef float    f32x4 __attribute__((ext_vector_type(4)));
typedef _Float16 f16x8 __attribute__((ext_vector_type(8)));

constexpr int S_PTS = 32768;
constexpr int DIM   = 64;
constexpr int HC    = 32;   // H*2
constexpr int TPW   = 16;   // time points per wave (MFMA M)
constexpr float INV_2PI = 0.15915494309189535f;

static __device__ __forceinline__ unsigned pkrtz(float x, float y) {
    return __builtin_bit_cast(unsigned, __builtin_amdgcn_cvt_pkrtz(x, y));
}
static __device__ __forceinline__ f16x8 pack8(float4 a, float4 b) {
    union { unsigned u[4]; f16x8 v; } t;
    t.u[0] = pkrtz(a.x, a.y);
    t.u[1] = pkrtz(a.z, a.w);
    t.u[2] = pkrtz(b.x, b.y);
    t.u[3] = pkrtz(b.z, b.w);
    return t.v;
}

__global__ __launch_bounds__(256, 2)
void fourier_fused(const float* __restrict__ s,
                   const float* __restrict__ A,
                   const float* __restrict__ phi,
                   const float* __restrict__ w,
                   const float* __restrict__ Wm,
                   const float* __restrict__ b,
                   float* __restrict__ out)
{
    __shared__ float slab[4][TPW * DIM];   // 4 KB per wave, wave-private

    const int lane = threadIdx.x & 63;
    const int wid  = threadIdx.x >> 6;
    const int t0   = (blockIdx.x * 4 + wid) * TPW;
    const int t16  = lane & 15;
    const int hi   = lane >> 4;

    // ---- Fourier params (lane = d), scaled to revolutions, packed f32x2 ----
    f32x2 a2[16], w2[16], p2[16];
    {
        const float4* A4 = reinterpret_cast<const float4*>(A   + lane * HC);
        const float4* P4 = reinterpret_cast<const float4*>(phi + lane * HC);
        const float4* W4 = reinterpret_cast<const float4*>(w   + lane * HC);
        #pragma unroll
        for (int q = 0; q < 8; ++q) {
            float4 av = A4[q], pv = P4[q], wv = W4[q];
            a2[2*q+0] = f32x2{av.x, av.y};           a2[2*q+1] = f32x2{av.z, av.w};
            p2[2*q+0] = f32x2{pv.x, pv.y} * INV_2PI; p2[2*q+1] = f32x2{pv.z, pv.w} * INV_2PI;
            w2[2*q+0] = f32x2{wv.x, wv.y} * INV_2PI; w2[2*q+1] = f32x2{wv.z, wv.w} * INV_2PI;
        }
    }

    // ---- B-operand fragments: wf[n][ks] holds W[n*16+t16][ks*32+hi*8 .. +7] ----
    // MFMA B layout (16x16x32): col = lane&15, k = (lane>>4)*8 + j
    f16x8 wf[4][2];
    float bj[4];
    #pragma unroll
    for (int n = 0; n < 4; ++n) {
        const float* wr = Wm + (n * 16 + t16) * DIM;
        #pragma unroll
        for (int ks = 0; ks < 2; ++ks) {
            float4 v0 = *reinterpret_cast<const float4*>(wr + ks * 32 + hi * 8);
            float4 v1 = *reinterpret_cast<const float4*>(wr + ks * 32 + hi * 8 + 4);
            wf[n][ks] = pack8(v0, v1);
        }
        bj[n] = b[n * 16 + t16];
    }

    // lanes 0..15 hold the wave's 16 time values
    const float sv = s[t0 + t16];
    float* myslab = slab[wid];

    // ---- phase A: 16 Fourier sums -> swizzled LDS slab ----
    // write word index: (k*64 + d) ^ ((k&7)<<2)  -> 2-way banks (free)
    #pragma unroll
    for (int k = 0; k < TPW; ++k) {
        const float st = __uint_as_float(__builtin_amdgcn_readlane(__float_as_uint(sv), k));
        const f32x2 st2 = {st, st};
        f32x2 ac0 = {0.f, 0.f}, ac1 = {0.f, 0.f};
        #pragma unroll
        for (int i = 0; i < 16; i += 2) {
            f32x2 ph0 = w2[i+0] * st2 + p2[i+0];   // v_pk_fma_f32
            f32x2 ph1 = w2[i+1] * st2 + p2[i+1];
            f32x2 c0 = { __builtin_amdgcn_cosf(ph0[0]), __builtin_amdgcn_cosf(ph0[1]) };
            f32x2 c1 = { __builtin_amdgcn_cosf(ph1[0]), __builtin_amdgcn_cosf(ph1[1]) };
            ac0 = a2[i+0] * c0 + ac0;
            ac1 = a2[i+1] * c1 + ac1;
        }
        const f32x2 acs = ac0 + ac1;
        myslab[(k * 64 + lane) ^ ((k & 7) << 2)] = acs[0] + acs[1];
    }
    asm volatile("s_waitcnt lgkmcnt(0)" ::: "memory");

    // ---- phase C: A-fragments from swizzled slab, 8 MFMAs ----
    // MFMA A layout (16x16x32): row = lane&15, k = (lane>>4)*8 + j
    f16x8 pa[2];
    #pragma unroll
    for (int ks = 0; ks < 2; ++ks) {
        const int base = t16 * 64 + ks * 32 + hi * 8;
        const int w0 = base       ^ ((t16 & 7) << 2);
        const int w1 = (base + 4) ^ ((t16 & 7) << 2);
        float4 q0 = *reinterpret_cast<const float4*>(myslab + w0);
        float4 q1 = *reinterpret_cast<const float4*>(myslab + w1);
        pa[ks] = pack8(q0, q1);
    }

    f32x4 acc0 = {}, acc1 = {}, acc2 = {}, acc3 = {};
    acc0 = __builtin_amdgcn_mfma_f32_16x16x32_f16(pa[0], wf[0][0], acc0, 0, 0, 0);
    acc0 = __builtin_amdgcn_mfma_f32_16x16x32_f16(pa[1], wf[0][1], acc0, 0, 0, 0);
    acc1 = __builtin_amdgcn_mfma_f32_16x16x32_f16(pa[0], wf[1][0], acc1, 0, 0, 0);
    acc1 = __builtin_amdgcn_mfma_f32_16x16x32_f16(pa[1], wf[1][1], acc1, 0, 0, 0);
    acc2 = __builtin_amdgcn_mfma_f32_16x16x32_f16(pa[0], wf[2][0], acc2, 0, 0, 0);
    acc2 = __builtin_amdgcn_mfma_f32_16x16x32_f16(pa[1], wf[2][1], acc2, 0, 0, 0);
    acc3 = __builtin_amdgcn_mfma_f32_16x16x32_f16(pa[0], wf[3][0], acc3, 0, 0, 0);
    acc3 = __builtin_amdgcn_mfma_f32_16x16x32_f16(pa[1], wf[3][1], acc3, 0, 0, 0);

    // ---- store: D layout col = lane&15, row = (lane>>4)*4 + reg ----
    #pragma unroll
    for (int r = 0; r < 4; ++r) {
        const int trow = (t0 + hi * 4 + r) * DIM;
        out[trow +  0 + t16] = acc0[r] + bj[0];
        out[trow + 16 + t16] = acc1[r] + bj[1];
        out[trow + 32 + t16] = acc2[r] + bj[2];
        out[trow + 48 + t16] = acc3[r] + bj[3];
    }
}

extern "C" void kernel_launch(void* const* d_in, const int* in_sizes, int n_in,
                              void* d_out, int out_size, void* d_ws, size_t ws_size,
                              hipStream_t stream) {
    const float* s   = (const float*)d_in[0];
    // d_in[1] is x — unused by the forward pass
    const float* A   = (const float*)d_in[2];
    const float* phi = (const float*)d_in[3];
    const float* w   = (const float*)d_in[4];
    const float* Wm  = (const float*)d_in[5];
    const float* b   = (const float*)d_in[6];
    float* out = (float*)d_out;

    dim3 grid(S_PTS / (4 * TPW));  // 512 blocks x 4 waves x 16 t = 32768
    dim3 block(256);
    hipLaunchKernelGGL(fourier_fused, grid, block, 0, stream,
                       s, A, phi, w, Wm, b, out);
}